// Round 3
// baseline (4630.029 us; speedup 1.0000x reference)
//
#include <hip/hip_runtime.h>

// Sparse 3D UNet forward (fp32). Round 3: LDS-free implicit GEMM.
// lane = output row; acc[COUT/4] float4 per lane; G: per-lane global float4
// gather; W: wave-uniform loads (compiler -> s_load, scalar pipe broadcast).
// EPI: 0 = relu(y*s+b); 1 = +skip; 2 = relu(...) + pair-reduce(cat).

template<int CIN_A, int CIN_B, int COUT, int EPI, bool SPLIT>
__global__ __launch_bounds__(256) void spconv(
    const float* __restrict__ inA,
    const float* __restrict__ inB,
    const int*   __restrict__ nbr,   // [N][27]
    const float* __restrict__ W,     // [27][CIN][COUT]
    const float* __restrict__ bn,    // [2][COUT]
    const float* __restrict__ skip,  // EPI==1 residual
    float*       __restrict__ out,   // [N][COUT] (non-split)
    float*       __restrict__ pout,  // [KS][N][COUT] partials (split)
    int N, int KS)
{
    constexpr int CIN = CIN_A + CIN_B;
    constexpr int NQ  = COUT / 4;       // float4 accumulators per lane

    const int lane = threadIdx.x & 63;
    const int wid  = threadIdx.x >> 6;

    // bijective XCD-aware swizzle (m204)
    unsigned nwg = gridDim.x;
    unsigned q8 = nwg / 8u, r8 = nwg % 8u;
    unsigned xcd = blockIdx.x % 8u, sub = blockIdx.x / 8u;
    unsigned id = (xcd < r8 ? xcd * (q8 + 1u) : r8 * (q8 + 1u) + (xcd - r8) * q8) + sub;

    int kg, rb;
    if (SPLIT) { kg = (int)(id % (unsigned)KS); rb = (int)(id / (unsigned)KS); }
    else       { kg = 0;  rb = (int)id; }
    const int kper = SPLIT ? 27 / KS : 27;
    const int k0 = kg * kper, k1 = k0 + kper;

    const int row = rb * 256 + wid * 64 + lane;
    const bool rv = row < N;
    const int* nbrp = nbr + (size_t)row * 27;

    float4 acc[NQ];
    #pragma unroll
    for (int q = 0; q < NQ; ++q) acc[q] = make_float4(0.f, 0.f, 0.f, 0.f);

    int idx = rv ? nbrp[k0] : -1;
    for (int k = k0; k < k1; ++k) {
        const int nidx = (rv && k + 1 < k1) ? nbrp[k + 1] : -1;  // prefetch
        const float* wb = W + (size_t)k * CIN * COUT;
        const float  mk = (idx >= 0) ? 1.f : 0.f;
        const int    si = (idx >= 0) ? idx : 0;

        auto do4 = [&](float4 g, const float* wci) {   // one float4 of G (4 ci)
            g.x *= mk; g.y *= mk; g.z *= mk; g.w *= mk;
            #pragma unroll
            for (int j = 0; j < 4; ++j) {
                const float gv = (&g.x)[j];
                const float4* wr = (const float4*)(wci + j * COUT);
                #pragma unroll
                for (int q = 0; q < NQ; ++q) {
                    float4 w = wr[q];
                    acc[q].x += gv * w.x; acc[q].y += gv * w.y;
                    acc[q].z += gv * w.z; acc[q].w += gv * w.w;
                }
            }
        };

        const float* rA = inA + (size_t)si * CIN_A;
        #pragma unroll 2
        for (int c4 = 0; c4 < CIN_A / 4; ++c4)
            do4(*(const float4*)(rA + c4 * 4), wb + (size_t)(c4 * 4) * COUT);
        if (CIN_B > 0) {
            const float* rB = inB + (size_t)si * CIN_B;
            #pragma unroll 2
            for (int c4 = 0; c4 < CIN_B / 4; ++c4)
                do4(*(const float4*)(rB + c4 * 4), wb + (size_t)(CIN_A + c4 * 4) * COUT);
        }
        idx = nidx;
    }

    if (SPLIT) {
        if (rv) {
            float* pp = pout + ((size_t)kg * N + row) * COUT;
            #pragma unroll
            for (int q = 0; q < NQ; ++q) *(float4*)(pp + q * 4) = acc[q];
        }
        return;
    }
    if (!rv) return;

    float*       op   = out + (size_t)row * COUT;
    const float* skp  = (EPI == 1) ? skip + (size_t)row * COUT : nullptr;
    const float* catA = inA + (size_t)row * CIN_A;
    const float* catB = (CIN_B > 0) ? inB + (size_t)row * CIN_B : nullptr;

    #pragma unroll
    for (int q = 0; q < NQ; ++q) {
        float4 sc = *(const float4*)(bn + q * 4);
        float4 bi = *(const float4*)(bn + COUT + q * 4);
        float4 y;
        y.x = acc[q].x * sc.x + bi.x;
        y.y = acc[q].y * sc.y + bi.y;
        y.z = acc[q].z * sc.z + bi.z;
        y.w = acc[q].w * sc.w + bi.w;
        if (EPI == 1) {
            float4 s = *(const float4*)(skp + q * 4);
            y.x += s.x; y.y += s.y; y.z += s.z; y.w += s.w;
        }
        y.x = fmaxf(y.x, 0.f); y.y = fmaxf(y.y, 0.f);
        y.z = fmaxf(y.z, 0.f); y.w = fmaxf(y.w, 0.f);
        if (EPI == 2) {
            const float* rs = (8 * q < CIN_A) ? catA + 8 * q : catB + 8 * q - CIN_A;
            float4 p0 = ((const float4*)rs)[0];
            float4 p1 = ((const float4*)rs)[1];
            y.x += p0.x + p0.y; y.y += p0.z + p0.w;
            y.z += p1.x + p1.y; y.w += p1.z + p1.w;
        }
        *(float4*)(op + q * 4) = y;
    }
}

// Sum split-K partials + BN/ReLU/skip/pair-reduce epilogue.
template<int CIN_A, int CIN_B, int COUT, int EPI>
__global__ __launch_bounds__(256) void epi_k(
    const float* __restrict__ P, int KS,
    const float* __restrict__ bn,
    const float* __restrict__ skip,
    const float* __restrict__ inA,
    const float* __restrict__ inB,
    float* __restrict__ out, int N)
{
    int t = blockIdx.x * 256 + threadIdx.x;
    int total = N * (COUT / 4);
    if (t >= total) return;
    int r   = t / (COUT / 4);
    int co0 = (t % (COUT / 4)) * 4;

    float4 y = make_float4(0.f, 0.f, 0.f, 0.f);
    for (int kg = 0; kg < KS; ++kg) {
        float4 p = *(const float4*)(P + ((size_t)kg * N + r) * COUT + co0);
        y.x += p.x; y.y += p.y; y.z += p.z; y.w += p.w;
    }
    float4 sc = *(const float4*)(bn + co0);
    float4 bi = *(const float4*)(bn + COUT + co0);
    y.x = y.x * sc.x + bi.x; y.y = y.y * sc.y + bi.y;
    y.z = y.z * sc.z + bi.z; y.w = y.w * sc.w + bi.w;
    if (EPI == 1) {
        float4 s = *(const float4*)(skip + (size_t)r * COUT + co0);
        y.x += s.x; y.y += s.y; y.z += s.z; y.w += s.w;
    }
    y.x = fmaxf(y.x, 0.f); y.y = fmaxf(y.y, 0.f);
    y.z = fmaxf(y.z, 0.f); y.w = fmaxf(y.w, 0.f);
    if (EPI == 2) {
        const float* rs = (2 * co0 < CIN_A)
            ? inA + (size_t)r * CIN_A + 2 * co0
            : inB + (size_t)r * CIN_B + 2 * co0 - CIN_A;
        float4 p0 = ((const float4*)rs)[0];
        float4 p1 = ((const float4*)rs)[1];
        y.x += p0.x + p0.y; y.y += p0.z + p0.w;
        y.z += p1.x + p1.y; y.w += p1.z + p1.w;
    }
    *(float4*)(out + (size_t)r * COUT + co0) = y;
}

// smallest KS in {1,3,9,27} giving >=600 blocks, then shrink to fit ws budget
static inline int ksel(int nblk, int N, int CO, size_t prem_elems) {
    int ks = 27;
    if (nblk >= 600) ks = 1;
    else if (nblk * 3 >= 600) ks = 3;
    else if (nblk * 9 >= 600) ks = 9;
    while (ks > 1 && (size_t)ks * (size_t)N * (size_t)CO > prem_elems) ks /= 3;
    return ks;
}

extern "C" void kernel_launch(void* const* d_in, const int* in_sizes, int n_in,
                              void* d_out, int out_size, void* d_ws, size_t ws_size,
                              hipStream_t stream)
{
    (void)n_in; (void)out_size;
    const float* vf     = (const float*)d_in[0];
    const float* Win    = (const float*)d_in[1];
    const float* W32    = (const float*)d_in[2];
    const float* W64    = (const float*)d_in[3];
    const float* Wd3    = (const float*)d_in[4];
    const float* W6432  = (const float*)d_in[5];
    const float* W12864 = (const float*)d_in[6];
    const float* bn32   = (const float*)d_in[7];
    const float* bn64   = (const float*)d_in[8];
    const int* nbr1  = (const int*)d_in[9];
    const int* nbr2  = (const int*)d_in[10];
    const int* nbr3  = (const int*)d_in[11];
    const int* nbr4  = (const int*)d_in[12];
    const int* nbrd2 = (const int*)d_in[13];
    const int* nbrd3 = (const int*)d_in[14];
    const int* nbrd4 = (const int*)d_in[15];
    const int* nbri4 = (const int*)d_in[16];
    const int* nbri3 = (const int*)d_in[17];
    const int* nbri2 = (const int*)d_in[18];

    const int N1 = in_sizes[9]  / 27;
    const int N2 = in_sizes[10] / 27;
    const int N3 = in_sizes[11] / 27;
    const int N4 = in_sizes[12] / 27;

    float* ws = (float*)d_ws;
    size_t off = 0;
    auto alloc = [&](size_t n) { float* p = ws + off; off += n; return p; };
    float* X1  = alloc((size_t)N1 * 32);
    float* TA  = alloc((size_t)N1 * 32);
    float* TA2 = alloc((size_t)N1 * 32);
    float* TU1 = alloc((size_t)N1 * 32);
    float* X2  = alloc((size_t)N2 * 32);
    float* TB2 = alloc((size_t)N2 * 32);
    float* TC2 = alloc((size_t)N2 * 32);
    float* TU2 = alloc((size_t)N2 * 32);
    float* X3  = alloc((size_t)N3 * 64);
    float* TB3 = alloc((size_t)N3 * 64);
    float* TC3 = alloc((size_t)N3 * 64);
    float* TU3 = alloc((size_t)N3 * 64);
    float* X4  = alloc((size_t)N4 * 64);
    float* TB4 = alloc((size_t)N4 * 64);
    float* TC4 = alloc((size_t)N4 * 64);
    float* OUT = (float*)d_out;

    // remaining ws elements available for split-K partials (small safety margin)
    size_t prem = (ws_size / 4 > off + 1024) ? (ws_size / 4 - off - 1024) : 0;
    float* P = ws + off;

    const size_t S32 = 27*32*32, S64 = (size_t)27*64*64, S6432 = (size_t)27*64*32, S12864 = (size_t)27*128*64;

#define CONV(CA, CB, CO, EP, pA, pB, pN, pW, pBN, pS, pO, NN) do {                      \
        int nblk_ = ((NN) + 255) / 256;                                                 \
        int ks_ = ksel(nblk_, (NN), (CO), prem);                                        \
        if (ks_ == 1) {                                                                 \
            spconv<CA, CB, CO, EP, false><<<dim3((unsigned)nblk_), 256, 0, stream>>>(   \
                pA, pB, pN, pW, pBN, pS, pO, nullptr, NN, 1);                           \
        } else {                                                                        \
            spconv<CA, CB, CO, EP, true><<<dim3((unsigned)(nblk_ * ks_)), 256, 0, stream>>>( \
                pA, pB, pN, pW, pBN, pS, nullptr, P, NN, ks_);                          \
            int tot4_ = (NN) * ((CO) / 4);                                              \
            epi_k<CA, CB, CO, EP><<<dim3((unsigned)((tot4_ + 255) / 256)), 256, 0, stream>>>( \
                P, ks_, pBN, pS, pA, pB, pO, NN);                                       \
        }                                                                               \
    } while (0)

    // ---------------- encoder ----------------
    CONV(4,0,32,0,  vf,  nullptr, nbr1,  Win,         bn32+0*64,  nullptr, TA,  N1);
    CONV(32,0,32,0, TA,  nullptr, nbr1,  W32+0*S32,   bn32+1*64,  nullptr, X1,  N1);
    CONV(32,0,32,0, X1,  nullptr, nbrd2, W32+1*S32,   bn32+2*64,  nullptr, TB2, N2);
    CONV(32,0,32,0, TB2, nullptr, nbr2,  W32+2*S32,   bn32+3*64,  nullptr, TC2, N2);
    CONV(32,0,32,0, TC2, nullptr, nbr2,  W32+3*S32,   bn32+4*64,  nullptr, X2,  N2);
    CONV(32,0,64,0, X2,  nullptr, nbrd3, Wd3,         bn64+0*128, nullptr, TB3, N3);
    CONV(64,0,64,0, TB3, nullptr, nbr3,  W64+0*S64,   bn64+1*128, nullptr, TC3, N3);
    CONV(64,0,64,0, TC3, nullptr, nbr3,  W64+1*S64,   bn64+2*128, nullptr, X3,  N3);
    CONV(64,0,64,0, X3,  nullptr, nbrd4, W64+2*S64,   bn64+3*128, nullptr, TB4, N4);
    CONV(64,0,64,0, TB4, nullptr, nbr4,  W64+3*S64,   bn64+4*128, nullptr, TC4, N4);
    CONV(64,0,64,0, TC4, nullptr, nbr4,  W64+4*S64,   bn64+5*128, nullptr, X4,  N4);
    // ---------------- bottleneck ----------------
    CONV(64,0,64,0, X4,  nullptr, nbr4,  W64+5*S64,   bn64+6*128, nullptr, TB4, N4);
    CONV(64,0,64,1, TB4, nullptr, nbr4,  W64+6*S64,   bn64+7*128, X4,      TC4, N4);
    CONV(64,64,64,2, X4, TC4,     nbr4,  W12864+0*S12864, bn64+11*128, nullptr, TB4, N4);
    // ---------------- decoder: 4 -> 3 ----------------
    CONV(64,0,64,0, TB4, nullptr, nbri4, W64+7*S64,   bn64+8*128, nullptr, TU3, N3);
    CONV(64,0,64,0, X3,  nullptr, nbr3,  W64+8*S64,   bn64+9*128, nullptr, TB3, N3);
    CONV(64,0,64,1, TB3, nullptr, nbr3,  W64+9*S64,   bn64+10*128, X3,     TC3, N3);
    CONV(64,64,64,2, TU3, TC3,    nbr3,  W12864+1*S12864, bn64+12*128, nullptr, TB3, N3);
    // ---------------- decoder: 3 -> 2 ----------------
    CONV(64,0,32,0, TB3, nullptr, nbri3, W6432+0*S6432, bn32+11*64, nullptr, TU2, N2);
    CONV(32,0,32,0, X2,  nullptr, nbr2,  W32+4*S32,   bn32+5*64,  nullptr, TB2, N2);
    CONV(32,0,32,1, TB2, nullptr, nbr2,  W32+5*S32,   bn32+6*64,  X2,      TC2, N2);
    CONV(32,32,32,2, TU2, TC2,    nbr2,  W6432+1*S6432, bn32+12*64, nullptr, TB2, N2);
    // ---------------- decoder: 2 -> 1 ----------------
    CONV(32,0,32,0, TB2, nullptr, nbri2, W32+6*S32,   bn32+7*64,  nullptr, TU1, N1);
    CONV(32,0,32,0, X1,  nullptr, nbr1,  W32+7*S32,   bn32+8*64,  nullptr, TA,  N1);
    CONV(32,0,32,1, TA,  nullptr, nbr1,  W32+8*S32,   bn32+9*64,  X1,      TA2, N1);
    CONV(32,32,32,2, TU1, TA2,    nbr1,  W6432+2*S6432, bn32+13*64, nullptr, TA,  N1);
    // ---------------- head ----------------
    CONV(32,0,32,0, TA,  nullptr, nbr1,  W32+9*S32,   bn32+10*64, nullptr, OUT, N1);
#undef CONV
}